// Round 1
// baseline (1976.462 us; speedup 1.0000x reference)
//
#include <hip/hip_runtime.h>
#include <math.h>

#define N_NODES 100000
#define N_EDGES 1600000
#define D 128
#define EPS 1e-5f
#define NB0 16
#define NB 16

// ---------------------------------------------------------------------------
// Edge scatter: mi[end] += w * x[start], mo[start] += w * x[end]
// 128 threads per edge (one per feature), 2 edges per 256-thread block.
// ---------------------------------------------------------------------------
__global__ void scatter_kernel(const float* __restrict__ x,
                               const float* __restrict__ ew,
                               const int* __restrict__ startv,
                               const int* __restrict__ endv,
                               float* __restrict__ mi,
                               float* __restrict__ mo) {
    long long tid = (long long)blockIdx.x * blockDim.x + threadIdx.x;
    int edge = (int)(tid >> 7);
    int f = (int)(tid & 127);
    if (edge >= N_EDGES) return;
    int s = startv[edge];
    int d = endv[edge];
    float w = ew[edge];
    float xs = x[(size_t)s * D + f];
    float xd = x[(size_t)d * D + f];
    atomicAdd(&mi[(size_t)d * D + f], w * xs);
    atomicAdd(&mo[(size_t)s * D + f], w * xd);
}

// ---------------------------------------------------------------------------
// Layer 0: h = tanh(LN(concat(mi,mo,x) @ W0 + b0)), K = 384
// 16 nodes per block, 128 threads; thread t owns output feature t.
// ---------------------------------------------------------------------------
__global__ void layer0_kernel(const float* __restrict__ mi,
                              const float* __restrict__ mo,
                              const float* __restrict__ x,
                              const float* __restrict__ W0,
                              const float* __restrict__ b0,
                              const float* __restrict__ g0,
                              const float* __restrict__ be0,
                              float* __restrict__ h) {
    __shared__ float sin_[NB0][3 * D];     // 24 KB
    __shared__ float sout[NB0][D + 1];     // padded: kills stride-128 conflicts
    __shared__ float smv[NB0][2];
    int t = threadIdx.x;                   // 0..127
    int node0 = blockIdx.x * NB0;

    for (int j = 0; j < NB0; ++j) {
        int n = node0 + j;
        sin_[j][t]         = mi[(size_t)n * D + t];
        sin_[j][D + t]     = mo[(size_t)n * D + t];
        sin_[j][2 * D + t] = x[(size_t)n * D + t];
    }
    __syncthreads();

    float acc[NB0];
#pragma unroll
    for (int j = 0; j < NB0; ++j) acc[j] = 0.f;

    for (int k = 0; k < 3 * D; ++k) {
        float wk = W0[(size_t)k * D + t];
#pragma unroll
        for (int j = 0; j < NB0; ++j) acc[j] += sin_[j][k] * wk;
    }

    float bias = b0[t];
#pragma unroll
    for (int j = 0; j < NB0; ++j) sout[j][t] = acc[j] + bias;
    __syncthreads();

    if (t < NB0) {
        float s = 0.f, s2 = 0.f;
        for (int k = 0; k < D; ++k) {
            float v = sout[t][k];
            s += v; s2 += v * v;
        }
        float m = s * (1.0f / D);
        float var = s2 * (1.0f / D) - m * m;
        smv[t][0] = m;
        smv[t][1] = rsqrtf(var + EPS);
    }
    __syncthreads();

    float gg = g0[t], bb = be0[t];
    for (int j = 0; j < NB0; ++j) {
        int n = node0 + j;
        float v = (sout[j][t] - smv[j][0]) * smv[j][1] * gg + bb;
        h[(size_t)n * D + t] = tanhf(v);
    }
}

// ---------------------------------------------------------------------------
// Layers 1..3: h = tanh(LN(h @ W + b)), K = 128. Safe in-place: each block
// reads exactly the 16 rows it later writes; no cross-block row sharing.
// ---------------------------------------------------------------------------
__global__ void layer_kernel(const float* hin,
                             const float* __restrict__ W,
                             const float* __restrict__ b,
                             const float* __restrict__ g,
                             const float* __restrict__ be,
                             float* hout) {
    __shared__ float sin_[NB][D];
    __shared__ float sout[NB][D + 1];
    __shared__ float smv[NB][2];
    int t = threadIdx.x;
    int node0 = blockIdx.x * NB;

    for (int j = 0; j < NB; ++j) {
        int n = node0 + j;
        sin_[j][t] = hin[(size_t)n * D + t];
    }
    __syncthreads();

    float acc[NB];
#pragma unroll
    for (int j = 0; j < NB; ++j) acc[j] = 0.f;

    for (int k = 0; k < D; ++k) {
        float wk = W[(size_t)k * D + t];
#pragma unroll
        for (int j = 0; j < NB; ++j) acc[j] += sin_[j][k] * wk;
    }

    float bias = b[t];
#pragma unroll
    for (int j = 0; j < NB; ++j) sout[j][t] = acc[j] + bias;
    __syncthreads();

    if (t < NB) {
        float s = 0.f, s2 = 0.f;
        for (int k = 0; k < D; ++k) {
            float v = sout[t][k];
            s += v; s2 += v * v;
        }
        float m = s * (1.0f / D);
        float var = s2 * (1.0f / D) - m * m;
        smv[t][0] = m;
        smv[t][1] = rsqrtf(var + EPS);
    }
    __syncthreads();

    float gg = g[t], bb = be[t];
    for (int j = 0; j < NB; ++j) {
        int n = node0 + j;
        float v = (sout[j][t] - smv[j][0]) * smv[j][1] * gg + bb;
        hout[(size_t)n * D + t] = tanhf(v);
    }
}

extern "C" void kernel_launch(void* const* d_in, const int* in_sizes, int n_in,
                              void* d_out, int out_size, void* d_ws, size_t ws_size,
                              hipStream_t stream) {
    const float* x   = (const float*)d_in[0];
    const float* e   = (const float*)d_in[1];
    const int*   ei  = (const int*)d_in[2];
    const float* W0  = (const float*)d_in[3];
    const float* b0  = (const float*)d_in[4];
    const float* g0  = (const float*)d_in[5];
    const float* be0 = (const float*)d_in[6];
    const float* W   = (const float*)d_in[7];
    const float* b   = (const float*)d_in[8];
    const float* g   = (const float*)d_in[9];
    const float* be  = (const float*)d_in[10];
    float* out = (float*)d_out;

    float* mi = (float*)d_ws;
    float* mo = mi + (size_t)N_NODES * D;

    // zero the two accumulation buffers (ws is re-poisoned to 0xAA each call)
    hipMemsetAsync(d_ws, 0, (size_t)2 * N_NODES * D * sizeof(float), stream);

    // scatter-add both directions
    {
        long long total = (long long)N_EDGES * D;
        int blocks = (int)((total + 255) / 256);
        scatter_kernel<<<blocks, 256, 0, stream>>>(x, e, ei, ei + N_EDGES, mi, mo);
    }

    // layer 0 (K=384) -> d_out
    layer0_kernel<<<N_NODES / NB0, 128, 0, stream>>>(mi, mo, x, W0, b0, g0, be0, out);

    // layers 1..3 (K=128), in-place on d_out
    for (int i = 0; i < 3; ++i) {
        layer_kernel<<<N_NODES / NB, 128, 0, stream>>>(
            out, W + (size_t)i * D * D, b + (size_t)i * D,
            g + (size_t)i * D, be + (size_t)i * D, out);
    }
}

// Round 2
// 1649.121 us; speedup vs baseline: 1.1985x; 1.1985x over previous
//
#include <hip/hip_runtime.h>
#include <math.h>

#define N_NODES 100000
#define N_EDGES 1600000
#define D 128
#define EPS 1e-5f
#define NB0 16
#define NB 16
#define NCNT (2 * N_NODES)                                   // in + out degree counters
#define SCAN_CHUNK 1024
#define SCAN_BLOCKS ((NCNT + SCAN_CHUNK - 1) / SCAN_CHUNK)   // 196
#define OFF_PAD (SCAN_BLOCKS * SCAN_CHUNK + 1)               // padded offsets array

// ---------------------------------------------------------------------------
// CSR build step 1: degree histogram. cnt[0..N) = in-degree, cnt[N..2N) = out.
// ---------------------------------------------------------------------------
__global__ void hist_kernel(const int* __restrict__ sv, const int* __restrict__ dv,
                            int* __restrict__ cnt) {
    int e = blockIdx.x * blockDim.x + threadIdx.x;
    if (e >= N_EDGES) return;
    atomicAdd(&cnt[dv[e]], 1);
    atomicAdd(&cnt[N_NODES + sv[e]], 1);
}

// ---------------------------------------------------------------------------
// CSR build step 2: exclusive scan of cnt (length 2N) -> off (length 2N+1).
// Three-kernel scan: per-block inclusive, scan of block sums, add offsets.
// ---------------------------------------------------------------------------
__global__ void scan_a(const int* __restrict__ cnt, int* __restrict__ off,
                       int* __restrict__ aux) {
    __shared__ int lds[256];
    int tid = threadIdx.x;
    int base = blockIdx.x * SCAN_CHUNK + tid * 4;
    int v0 = (base + 0 < NCNT) ? cnt[base + 0] : 0;
    int v1 = (base + 1 < NCNT) ? cnt[base + 1] : 0;
    int v2 = (base + 2 < NCNT) ? cnt[base + 2] : 0;
    int v3 = (base + 3 < NCNT) ? cnt[base + 3] : 0;
    int tot = v0 + v1 + v2 + v3;
    lds[tid] = tot;
    __syncthreads();
    for (int s = 1; s < 256; s <<= 1) {
        int add = (tid >= s) ? lds[tid - s] : 0;
        __syncthreads();
        lds[tid] += add;
        __syncthreads();
    }
    int excl = lds[tid] - tot;
    off[base + 1] = excl + v0;
    off[base + 2] = excl + v0 + v1;
    off[base + 3] = excl + v0 + v1 + v2;
    off[base + 4] = excl + tot;
    if (tid == 255) aux[blockIdx.x] = lds[255];
}

__global__ void scan_b(int* __restrict__ aux) {
    __shared__ int lds[256];
    int tid = threadIdx.x;
    int v = (tid < SCAN_BLOCKS) ? aux[tid] : 0;
    lds[tid] = v;
    __syncthreads();
    for (int s = 1; s < 256; s <<= 1) {
        int add = (tid >= s) ? lds[tid - s] : 0;
        __syncthreads();
        lds[tid] += add;
        __syncthreads();
    }
    aux[tid] = lds[tid] - v;   // exclusive
}

__global__ void scan_c(int* __restrict__ off, const int* __restrict__ aux) {
    int tid = threadIdx.x;
    int add = aux[blockIdx.x];
    int base = blockIdx.x * SCAN_CHUNK + tid * 4;
    off[base + 1] += add;
    off[base + 2] += add;
    off[base + 3] += add;
    off[base + 4] += add;
    if (blockIdx.x == 0 && tid == 0) off[0] = 0;
}

// ---------------------------------------------------------------------------
// CSR build step 3: fill lists. lsrc/lw[0..E) = in-edges grouped by dst
// (payload: src node, weight); [E..2E) = out-edges grouped by src (payload:
// dst node, weight). Slot = off[node] + (remaining-count - 1) via atomicSub.
// ---------------------------------------------------------------------------
__global__ void fill_kernel(const int* __restrict__ sv, const int* __restrict__ dv,
                            const float* __restrict__ ew, const int* __restrict__ off,
                            int* __restrict__ cnt, int* __restrict__ lsrc,
                            float* __restrict__ lw) {
    int e = blockIdx.x * blockDim.x + threadIdx.x;
    if (e >= N_EDGES) return;
    int s = sv[e], d = dv[e];
    float w = ew[e];
    int c = atomicSub(&cnt[d], 1);
    int pos = off[d] + c - 1;
    lsrc[pos] = s;
    lw[pos] = w;
    int c2 = atomicSub(&cnt[N_NODES + s], 1);
    int pos2 = off[N_NODES + s] + c2 - 1;
    lsrc[pos2] = d;
    lw[pos2] = w;
}

// ---------------------------------------------------------------------------
// Layer 0 fused with gather: per node, mi/mo accumulated from CSR lists
// (no atomics), then h = tanh(LN(concat(mi,mo,x) @ W0 + b0)).
// 16 nodes/block, 128 threads; thread t owns feature t.
// ---------------------------------------------------------------------------
__global__ void layer0_fused(const float* __restrict__ x, const int* __restrict__ off,
                             const int* __restrict__ lsrc, const float* __restrict__ lw,
                             const float* __restrict__ W0, const float* __restrict__ b0,
                             const float* __restrict__ g0, const float* __restrict__ be0,
                             float* __restrict__ h) {
    __shared__ __align__(16) float sin_[NB0][3 * D];   // 24 KB
    __shared__ float sout[NB0][D + 1];
    __shared__ float smv[NB0][2];
    int t = threadIdx.x;
    int node0 = blockIdx.x * NB0;

    for (int j = 0; j < NB0; ++j) {
        int n = node0 + j;
        float ami0 = 0.f, ami1 = 0.f;
        int e0 = off[n], e1 = off[n + 1];
        int e = e0;
        for (; e + 1 < e1; e += 2) {
            ami0 += lw[e] * x[(size_t)lsrc[e] * D + t];
            ami1 += lw[e + 1] * x[(size_t)lsrc[e + 1] * D + t];
        }
        if (e < e1) ami0 += lw[e] * x[(size_t)lsrc[e] * D + t];
        float amo0 = 0.f, amo1 = 0.f;
        int f0 = off[N_NODES + n], f1 = off[N_NODES + n + 1];
        int f = f0;
        for (; f + 1 < f1; f += 2) {
            amo0 += lw[f] * x[(size_t)lsrc[f] * D + t];
            amo1 += lw[f + 1] * x[(size_t)lsrc[f + 1] * D + t];
        }
        if (f < f1) amo0 += lw[f] * x[(size_t)lsrc[f] * D + t];
        sin_[j][t]         = ami0 + ami1;
        sin_[j][D + t]     = amo0 + amo1;
        sin_[j][2 * D + t] = x[(size_t)n * D + t];
    }
    __syncthreads();

    float acc[NB0];
#pragma unroll
    for (int j = 0; j < NB0; ++j) acc[j] = 0.f;

    for (int k = 0; k < 3 * D; k += 4) {
        float w0 = W0[(size_t)(k + 0) * D + t];
        float w1 = W0[(size_t)(k + 1) * D + t];
        float w2 = W0[(size_t)(k + 2) * D + t];
        float w3 = W0[(size_t)(k + 3) * D + t];
#pragma unroll
        for (int j = 0; j < NB0; ++j) {
            float4 s4 = *(const float4*)&sin_[j][k];
            acc[j] = fmaf(s4.w, w3, fmaf(s4.z, w2, fmaf(s4.y, w1, fmaf(s4.x, w0, acc[j]))));
        }
    }

    float bias = b0[t];
#pragma unroll
    for (int j = 0; j < NB0; ++j) sout[j][t] = acc[j] + bias;
    __syncthreads();

    if (t < NB0) {
        float s = 0.f, s2 = 0.f;
        for (int k = 0; k < D; ++k) {
            float v = sout[t][k];
            s += v; s2 += v * v;
        }
        float m = s * (1.0f / D);
        float var = s2 * (1.0f / D) - m * m;
        smv[t][0] = m;
        smv[t][1] = rsqrtf(var + EPS);
    }
    __syncthreads();

    float gg = g0[t], bb = be0[t];
    for (int j = 0; j < NB0; ++j) {
        int n = node0 + j;
        float v = (sout[j][t] - smv[j][0]) * smv[j][1] * gg + bb;
        h[(size_t)n * D + t] = tanhf(v);
    }
}

// ---------------------------------------------------------------------------
// Layers 1..3: h = tanh(LN(h @ W + b)), K = 128, in-place safe (block reads
// exactly the rows it writes). float4 LDS reads in the K loop.
// ---------------------------------------------------------------------------
__global__ void layer_kernel(const float* hin,
                             const float* __restrict__ W,
                             const float* __restrict__ b,
                             const float* __restrict__ g,
                             const float* __restrict__ be,
                             float* hout) {
    __shared__ __align__(16) float sin_[NB][D];
    __shared__ float sout[NB][D + 1];
    __shared__ float smv[NB][2];
    int t = threadIdx.x;
    int node0 = blockIdx.x * NB;

    for (int j = 0; j < NB; ++j) {
        int n = node0 + j;
        sin_[j][t] = hin[(size_t)n * D + t];
    }
    __syncthreads();

    float acc[NB];
#pragma unroll
    for (int j = 0; j < NB; ++j) acc[j] = 0.f;

    for (int k = 0; k < D; k += 4) {
        float w0 = W[(size_t)(k + 0) * D + t];
        float w1 = W[(size_t)(k + 1) * D + t];
        float w2 = W[(size_t)(k + 2) * D + t];
        float w3 = W[(size_t)(k + 3) * D + t];
#pragma unroll
        for (int j = 0; j < NB; ++j) {
            float4 s4 = *(const float4*)&sin_[j][k];
            acc[j] = fmaf(s4.w, w3, fmaf(s4.z, w2, fmaf(s4.y, w1, fmaf(s4.x, w0, acc[j]))));
        }
    }

    float bias = b[t];
#pragma unroll
    for (int j = 0; j < NB; ++j) sout[j][t] = acc[j] + bias;
    __syncthreads();

    if (t < NB) {
        float s = 0.f, s2 = 0.f;
        for (int k = 0; k < D; ++k) {
            float v = sout[t][k];
            s += v; s2 += v * v;
        }
        float m = s * (1.0f / D);
        float var = s2 * (1.0f / D) - m * m;
        smv[t][0] = m;
        smv[t][1] = rsqrtf(var + EPS);
    }
    __syncthreads();

    float gg = g[t], bb = be[t];
    for (int j = 0; j < NB; ++j) {
        int n = node0 + j;
        float v = (sout[j][t] - smv[j][0]) * smv[j][1] * gg + bb;
        hout[(size_t)n * D + t] = tanhf(v);
    }
}

extern "C" void kernel_launch(void* const* d_in, const int* in_sizes, int n_in,
                              void* d_out, int out_size, void* d_ws, size_t ws_size,
                              hipStream_t stream) {
    const float* x   = (const float*)d_in[0];
    const float* e   = (const float*)d_in[1];
    const int*   ei  = (const int*)d_in[2];
    const float* W0  = (const float*)d_in[3];
    const float* b0  = (const float*)d_in[4];
    const float* g0  = (const float*)d_in[5];
    const float* be0 = (const float*)d_in[6];
    const float* W   = (const float*)d_in[7];
    const float* b   = (const float*)d_in[8];
    const float* g   = (const float*)d_in[9];
    const float* be  = (const float*)d_in[10];
    float* out = (float*)d_out;

    const int* sv = ei;              // edge_index[0] = start
    const int* dv = ei + N_EDGES;    // edge_index[1] = end

    // workspace layout (~27 MB)
    int*   cnt  = (int*)d_ws;                    // NCNT
    int*   off  = cnt + NCNT;                    // OFF_PAD
    int*   aux  = off + OFF_PAD;                 // 256
    int*   lsrc = aux + 256;                     // 2*N_EDGES
    float* lw   = (float*)(lsrc + 2 * N_EDGES);  // 2*N_EDGES

    hipMemsetAsync(cnt, 0, NCNT * sizeof(int), stream);

    hist_kernel<<<(N_EDGES + 255) / 256, 256, 0, stream>>>(sv, dv, cnt);
    scan_a<<<SCAN_BLOCKS, 256, 0, stream>>>(cnt, off, aux);
    scan_b<<<1, 256, 0, stream>>>(aux);
    scan_c<<<SCAN_BLOCKS, 256, 0, stream>>>(off, aux);
    fill_kernel<<<(N_EDGES + 255) / 256, 256, 0, stream>>>(sv, dv, e, off, cnt, lsrc, lw);

    layer0_fused<<<N_NODES / NB0, 128, 0, stream>>>(x, off, lsrc, lw,
                                                    W0, b0, g0, be0, out);

    for (int i = 0; i < 3; ++i) {
        layer_kernel<<<N_NODES / NB, 128, 0, stream>>>(
            out, W + (size_t)i * D * D, b + (size_t)i * D,
            g + (size_t)i * D, be + (size_t)i * D, out);
    }
}

// Round 4
// 1172.051 us; speedup vs baseline: 1.6863x; 1.4070x over previous
//
#include <hip/hip_runtime.h>
#include <math.h>

#define N_NODES 100000
#define N_EDGES 1600000
#define D 128
#define EPS 1e-5f
#define NB0 16
#define NB 16
#define NCNT (2 * N_NODES)                                   // in + out degree counters
#define SCAN_CHUNK 1024
#define SCAN_BLOCKS ((NCNT + SCAN_CHUNK - 1) / SCAN_CHUNK)   // 196
#define OFF_PAD (SCAN_BLOCKS * SCAN_CHUNK + 1)
#define TASKS (2 * N_NODES)

// ---------------------------------------------------------------------------
// CSR build step 1: degree histogram. cnt[0..N) = in-degree, cnt[N..2N) = out.
// ---------------------------------------------------------------------------
__global__ void hist_kernel(const int* __restrict__ sv, const int* __restrict__ dv,
                            int* __restrict__ cnt) {
    int e = blockIdx.x * blockDim.x + threadIdx.x;
    if (e >= N_EDGES) return;
    atomicAdd(&cnt[dv[e]], 1);
    atomicAdd(&cnt[N_NODES + sv[e]], 1);
}

// ---------------------------------------------------------------------------
// CSR build step 2: exclusive scan of cnt (length 2N) -> off (length 2N+1).
// ---------------------------------------------------------------------------
__global__ void scan_a(const int* __restrict__ cnt, int* __restrict__ off,
                       int* __restrict__ aux) {
    __shared__ int lds[256];
    int tid = threadIdx.x;
    int base = blockIdx.x * SCAN_CHUNK + tid * 4;
    int v0 = (base + 0 < NCNT) ? cnt[base + 0] : 0;
    int v1 = (base + 1 < NCNT) ? cnt[base + 1] : 0;
    int v2 = (base + 2 < NCNT) ? cnt[base + 2] : 0;
    int v3 = (base + 3 < NCNT) ? cnt[base + 3] : 0;
    int tot = v0 + v1 + v2 + v3;
    lds[tid] = tot;
    __syncthreads();
    for (int s = 1; s < 256; s <<= 1) {
        int add = (tid >= s) ? lds[tid - s] : 0;
        __syncthreads();
        lds[tid] += add;
        __syncthreads();
    }
    int excl = lds[tid] - tot;
    off[base + 1] = excl + v0;
    off[base + 2] = excl + v0 + v1;
    off[base + 3] = excl + v0 + v1 + v2;
    off[base + 4] = excl + tot;
    if (tid == 255) aux[blockIdx.x] = lds[255];
}

__global__ void scan_b(int* __restrict__ aux) {
    __shared__ int lds[256];
    int tid = threadIdx.x;
    int v = (tid < SCAN_BLOCKS) ? aux[tid] : 0;
    lds[tid] = v;
    __syncthreads();
    for (int s = 1; s < 256; s <<= 1) {
        int add = (tid >= s) ? lds[tid - s] : 0;
        __syncthreads();
        lds[tid] += add;
        __syncthreads();
    }
    aux[tid] = lds[tid] - v;   // exclusive
}

__global__ void scan_c(int* __restrict__ off, const int* __restrict__ aux) {
    int tid = threadIdx.x;
    int add = aux[blockIdx.x];
    int base = blockIdx.x * SCAN_CHUNK + tid * 4;
    off[base + 1] += add;
    off[base + 2] += add;
    off[base + 3] += add;
    off[base + 4] += add;
    if (blockIdx.x == 0 && tid == 0) off[0] = 0;
}

// ---------------------------------------------------------------------------
// CSR build step 3: fill lists. [0..E) = in-edges grouped by dst (payload:
// src, w); [E..2E) = out-edges grouped by src (payload: dst, w).
// ---------------------------------------------------------------------------
__global__ void fill_kernel(const int* __restrict__ sv, const int* __restrict__ dv,
                            const float* __restrict__ ew, const int* __restrict__ off,
                            int* __restrict__ cnt, int* __restrict__ lsrc,
                            float* __restrict__ lw) {
    int e = blockIdx.x * blockDim.x + threadIdx.x;
    if (e >= N_EDGES) return;
    int s = sv[e], d = dv[e];
    float w = ew[e];
    int c = atomicSub(&cnt[d], 1);
    int pos = off[d] + c - 1;
    lsrc[pos] = s;
    lw[pos] = w;
    int c2 = atomicSub(&cnt[N_NODES + s], 1);
    int pos2 = off[N_NODES + s] + c2 - 1;
    lsrc[pos2] = d;
    lw[pos2] = w;
}

// ---------------------------------------------------------------------------
// Gather (full f32): one wave per task. task < N: mi row (ws); else mo row
// (d_out used as scratch). Wave preloads up to 64 (src,w) pairs into regs;
// 4 lane-groups of 16 process 4 edges concurrently, each lane reading 32 B
// of the 512 B f32 row. f32 accumulate, butterfly-reduce across groups.
// No LDS -> full occupancy, ~8 loads in flight per lane.
// ---------------------------------------------------------------------------
__global__ void gather_kernel(const float* __restrict__ x,
                              const int* __restrict__ off,
                              const int* __restrict__ lsrc,
                              const float* __restrict__ lw,
                              float* __restrict__ mi,
                              float* __restrict__ mo) {
    int wave = (int)((blockIdx.x * (unsigned)blockDim.x + threadIdx.x) >> 6);
    int lane = threadIdx.x & 63;
    if (wave >= TASKS) return;
    int g = lane >> 4;        // edge slot within quad
    int i = lane & 15;        // 32 B chunk within row
    int e0 = off[wave], e1 = off[wave + 1];

    float acc[8];
#pragma unroll
    for (int r = 0; r < 8; ++r) acc[r] = 0.f;

    for (int base = e0; base < e1; base += 64) {
        int src = 0;
        float w = 0.f;
        int idx = base + lane;
        if (idx < e1) {
            src = lsrc[idx];
            w = lw[idx];
        }
        int cnt = e1 - base;
        if (cnt > 64) cnt = 64;
        int jn = (cnt + 3) >> 2;
        for (int j = 0; j < jn; ++j) {
            int es = j * 4 + g;
            int s = __shfl(src, es);
            float ww = __shfl(w, es);
            const float4* row = (const float4*)(x + (size_t)s * D + i * 8);
            float4 a = row[0];
            float4 b = row[1];
            acc[0] = fmaf(ww, a.x, acc[0]);
            acc[1] = fmaf(ww, a.y, acc[1]);
            acc[2] = fmaf(ww, a.z, acc[2]);
            acc[3] = fmaf(ww, a.w, acc[3]);
            acc[4] = fmaf(ww, b.x, acc[4]);
            acc[5] = fmaf(ww, b.y, acc[5]);
            acc[6] = fmaf(ww, b.z, acc[6]);
            acc[7] = fmaf(ww, b.w, acc[7]);
        }
    }

#pragma unroll
    for (int r = 0; r < 8; ++r) {
        acc[r] += __shfl_xor(acc[r], 32);
        acc[r] += __shfl_xor(acc[r], 16);
    }
    if (g == 0) {
        float* dst = (wave < N_NODES) ? (mi + (size_t)wave * D)
                                      : (mo + (size_t)(wave - N_NODES) * D);
        float4* o = (float4*)(dst + i * 8);
        o[0] = make_float4(acc[0], acc[1], acc[2], acc[3]);
        o[1] = make_float4(acc[4], acc[5], acc[6], acc[7]);
    }
}

// ---------------------------------------------------------------------------
// Layer 0: h = tanh(LN(concat(mi,mo,x) @ W0 + b0)), K = 384.
// mo lives in d_out; output h also d_out — in-place safe (block reads exactly
// the 16 rows it writes, sync between load and store).
// ---------------------------------------------------------------------------
__global__ void layer0_kernel(const float* __restrict__ mi,
                              const float* mo,
                              const float* __restrict__ x,
                              const float* __restrict__ W0,
                              const float* __restrict__ b0,
                              const float* __restrict__ g0,
                              const float* __restrict__ be0,
                              float* h) {
    __shared__ __align__(16) float sin_[NB0][3 * D];
    __shared__ float sout[NB0][D + 1];
    __shared__ float smv[NB0][2];
    int t = threadIdx.x;
    int node0 = blockIdx.x * NB0;

    for (int j = 0; j < NB0; ++j) {
        int n = node0 + j;
        sin_[j][t]         = mi[(size_t)n * D + t];
        sin_[j][D + t]     = mo[(size_t)n * D + t];
        sin_[j][2 * D + t] = x[(size_t)n * D + t];
    }
    __syncthreads();

    float acc[NB0];
#pragma unroll
    for (int j = 0; j < NB0; ++j) acc[j] = 0.f;

    for (int k = 0; k < 3 * D; k += 4) {
        float w0 = W0[(size_t)(k + 0) * D + t];
        float w1 = W0[(size_t)(k + 1) * D + t];
        float w2 = W0[(size_t)(k + 2) * D + t];
        float w3 = W0[(size_t)(k + 3) * D + t];
#pragma unroll
        for (int j = 0; j < NB0; ++j) {
            float4 s4 = *(const float4*)&sin_[j][k];
            acc[j] = fmaf(s4.w, w3, fmaf(s4.z, w2, fmaf(s4.y, w1, fmaf(s4.x, w0, acc[j]))));
        }
    }

    float bias = b0[t];
#pragma unroll
    for (int j = 0; j < NB0; ++j) sout[j][t] = acc[j] + bias;
    __syncthreads();

    if (t < NB0) {
        float s = 0.f, s2 = 0.f;
        for (int k = 0; k < D; ++k) {
            float v = sout[t][k];
            s += v; s2 += v * v;
        }
        float m = s * (1.0f / D);
        float var = s2 * (1.0f / D) - m * m;
        smv[t][0] = m;
        smv[t][1] = rsqrtf(var + EPS);
    }
    __syncthreads();

    float gg = g0[t], bb = be0[t];
    for (int j = 0; j < NB0; ++j) {
        int n = node0 + j;
        float v = (sout[j][t] - smv[j][0]) * smv[j][1] * gg + bb;
        h[(size_t)n * D + t] = tanhf(v);
    }
}

// ---------------------------------------------------------------------------
// Layers 1..3: h = tanh(LN(h @ W + b)), K = 128, in-place safe.
// ---------------------------------------------------------------------------
__global__ void layer_kernel(const float* hin,
                             const float* __restrict__ W,
                             const float* __restrict__ b,
                             const float* __restrict__ g,
                             const float* __restrict__ be,
                             float* hout) {
    __shared__ __align__(16) float sin_[NB][D];
    __shared__ float sout[NB][D + 1];
    __shared__ float smv[NB][2];
    int t = threadIdx.x;
    int node0 = blockIdx.x * NB;

    for (int j = 0; j < NB; ++j) {
        int n = node0 + j;
        sin_[j][t] = hin[(size_t)n * D + t];
    }
    __syncthreads();

    float acc[NB];
#pragma unroll
    for (int j = 0; j < NB; ++j) acc[j] = 0.f;

    for (int k = 0; k < D; k += 4) {
        float w0 = W[(size_t)(k + 0) * D + t];
        float w1 = W[(size_t)(k + 1) * D + t];
        float w2 = W[(size_t)(k + 2) * D + t];
        float w3 = W[(size_t)(k + 3) * D + t];
#pragma unroll
        for (int j = 0; j < NB; ++j) {
            float4 s4 = *(const float4*)&sin_[j][k];
            acc[j] = fmaf(s4.w, w3, fmaf(s4.z, w2, fmaf(s4.y, w1, fmaf(s4.x, w0, acc[j]))));
        }
    }

    float bias = b[t];
#pragma unroll
    for (int j = 0; j < NB; ++j) sout[j][t] = acc[j] + bias;
    __syncthreads();

    if (t < NB) {
        float s = 0.f, s2 = 0.f;
        for (int k = 0; k < D; ++k) {
            float v = sout[t][k];
            s += v; s2 += v * v;
        }
        float m = s * (1.0f / D);
        float var = s2 * (1.0f / D) - m * m;
        smv[t][0] = m;
        smv[t][1] = rsqrtf(var + EPS);
    }
    __syncthreads();

    float gg = g[t], bb = be[t];
    for (int j = 0; j < NB; ++j) {
        int n = node0 + j;
        float v = (sout[j][t] - smv[j][0]) * smv[j][1] * gg + bb;
        hout[(size_t)n * D + t] = tanhf(v);
    }
}

extern "C" void kernel_launch(void* const* d_in, const int* in_sizes, int n_in,
                              void* d_out, int out_size, void* d_ws, size_t ws_size,
                              hipStream_t stream) {
    const float* x   = (const float*)d_in[0];
    const float* e   = (const float*)d_in[1];
    const int*   ei  = (const int*)d_in[2];
    const float* W0  = (const float*)d_in[3];
    const float* b0  = (const float*)d_in[4];
    const float* g0  = (const float*)d_in[5];
    const float* be0 = (const float*)d_in[6];
    const float* W   = (const float*)d_in[7];
    const float* b   = (const float*)d_in[8];
    const float* g   = (const float*)d_in[9];
    const float* be  = (const float*)d_in[10];
    float* out = (float*)d_out;

    const int* sv = ei;              // edge_index[0] = start
    const int* dv = ei + N_EDGES;    // edge_index[1] = end

    // workspace layout (~78.4 MB); mo lives in d_out (51.2 MB scratch)
    char* p = (char*)d_ws;
    int*   cnt = (int*)p;   p += (size_t)NCNT * 4;          // 0.8 MB
    int*   off = (int*)p;   p += (size_t)OFF_PAD * 4;       // 0.8 MB
    int*   aux = (int*)p;   p += 256 * 4;
    int*   lsrc= (int*)p;   p += (size_t)2 * N_EDGES * 4;   // 12.8 MB
    float* lw  = (float*)p; p += (size_t)2 * N_EDGES * 4;   // 12.8 MB
    float* mi  = (float*)p;                                 // 51.2 MB
    float* mo  = out;                                       // d_out as scratch

    hipMemsetAsync(cnt, 0, NCNT * sizeof(int), stream);

    hist_kernel<<<(N_EDGES + 255) / 256, 256, 0, stream>>>(sv, dv, cnt);
    scan_a<<<SCAN_BLOCKS, 256, 0, stream>>>(cnt, off, aux);
    scan_b<<<1, 256, 0, stream>>>(aux);
    scan_c<<<SCAN_BLOCKS, 256, 0, stream>>>(off, aux);
    fill_kernel<<<(N_EDGES + 255) / 256, 256, 0, stream>>>(sv, dv, e, off, cnt, lsrc, lw);

    gather_kernel<<<TASKS / 4, 256, 0, stream>>>(x, off, lsrc, lw, mi, mo);

    layer0_kernel<<<N_NODES / NB0, 128, 0, stream>>>(mi, mo, x, W0, b0, g0, be0, out);

    for (int i = 0; i < 3; ++i) {
        layer_kernel<<<N_NODES / NB, 128, 0, stream>>>(
            out, W + (size_t)i * D * D, b + (size_t)i * D,
            g + (size_t)i * D, be + (size_t)i * D, out);
    }
}

// Round 5
// 837.078 us; speedup vs baseline: 2.3611x; 1.4002x over previous
//
#include <hip/hip_runtime.h>
#include <math.h>

#define N_NODES 100000
#define N_EDGES 1600000
#define D 128
#define EPS 1e-5f
#define NCNT (2 * N_NODES)
#define SCAN_CHUNK 1024
#define SCAN_BLOCKS ((NCNT + SCAN_CHUNK - 1) / SCAN_CHUNK)   // 196
#define OFF_PAD (SCAN_BLOCKS * SCAN_CHUNK + 1)
#define TASKS (2 * N_NODES)

#define K0 384
#define KL 128
#define PAD0 (K0 + 8)     // bf16 elems per LDS row, layer0
#define PADL (KL + 8)     // bf16 elems per LDS row, layers 1-3
#define SSTR 132          // f32 sout row stride (132%32==4 -> spread banks, 16B-aligned rows)

typedef unsigned short ushort_t;
typedef unsigned long long ull;
typedef short short8 __attribute__((ext_vector_type(8)));   // 8 bf16 = 4 VGPRs (MFMA A/B frag)
typedef float f32x4 __attribute__((ext_vector_type(4)));    // MFMA C/D frag

static __device__ __forceinline__ float bf2f(ushort_t u) {
    return __uint_as_float(((unsigned)u) << 16);
}
static __device__ __forceinline__ ushort_t f2bf(float f) {
    unsigned u = __float_as_uint(f);
    u += 0x7FFF + ((u >> 16) & 1);          // RNE
    return (ushort_t)(u >> 16);
}
static __device__ __forceinline__ float tanh_fast(float v) {
    return 1.0f - 2.0f / (__expf(2.0f * v) + 1.0f);   // exact at +-inf limits
}

// ---------------------------------------------------------------------------
// CSR build (unchanged from round 4)
// ---------------------------------------------------------------------------
__global__ void hist_kernel(const int* __restrict__ sv, const int* __restrict__ dv,
                            int* __restrict__ cnt) {
    int e = blockIdx.x * blockDim.x + threadIdx.x;
    if (e >= N_EDGES) return;
    atomicAdd(&cnt[dv[e]], 1);
    atomicAdd(&cnt[N_NODES + sv[e]], 1);
}

__global__ void scan_a(const int* __restrict__ cnt, int* __restrict__ off,
                       int* __restrict__ aux) {
    __shared__ int lds[256];
    int tid = threadIdx.x;
    int base = blockIdx.x * SCAN_CHUNK + tid * 4;
    int v0 = (base + 0 < NCNT) ? cnt[base + 0] : 0;
    int v1 = (base + 1 < NCNT) ? cnt[base + 1] : 0;
    int v2 = (base + 2 < NCNT) ? cnt[base + 2] : 0;
    int v3 = (base + 3 < NCNT) ? cnt[base + 3] : 0;
    int tot = v0 + v1 + v2 + v3;
    lds[tid] = tot;
    __syncthreads();
    for (int s = 1; s < 256; s <<= 1) {
        int add = (tid >= s) ? lds[tid - s] : 0;
        __syncthreads();
        lds[tid] += add;
        __syncthreads();
    }
    int excl = lds[tid] - tot;
    off[base + 1] = excl + v0;
    off[base + 2] = excl + v0 + v1;
    off[base + 3] = excl + v0 + v1 + v2;
    off[base + 4] = excl + tot;
    if (tid == 255) aux[blockIdx.x] = lds[255];
}

__global__ void scan_b(int* __restrict__ aux) {
    __shared__ int lds[256];
    int tid = threadIdx.x;
    int v = (tid < SCAN_BLOCKS) ? aux[tid] : 0;
    lds[tid] = v;
    __syncthreads();
    for (int s = 1; s < 256; s <<= 1) {
        int add = (tid >= s) ? lds[tid - s] : 0;
        __syncthreads();
        lds[tid] += add;
        __syncthreads();
    }
    aux[tid] = lds[tid] - v;
}

__global__ void scan_c(int* __restrict__ off, const int* __restrict__ aux) {
    int tid = threadIdx.x;
    int add = aux[blockIdx.x];
    int base = blockIdx.x * SCAN_CHUNK + tid * 4;
    off[base + 1] += add;
    off[base + 2] += add;
    off[base + 3] += add;
    off[base + 4] += add;
    if (blockIdx.x == 0 && tid == 0) off[0] = 0;
}

__global__ void fill_kernel(const int* __restrict__ sv, const int* __restrict__ dv,
                            const float* __restrict__ ew, const int* __restrict__ off,
                            int* __restrict__ cnt, int* __restrict__ lsrc,
                            float* __restrict__ lw) {
    int e = blockIdx.x * blockDim.x + threadIdx.x;
    if (e >= N_EDGES) return;
    int s = sv[e], d = dv[e];
    float w = ew[e];
    int c = atomicSub(&cnt[d], 1);
    int pos = off[d] + c - 1;
    lsrc[pos] = s;
    lw[pos] = w;
    int c2 = atomicSub(&cnt[N_NODES + s], 1);
    int pos2 = off[N_NODES + s] + c2 - 1;
    lsrc[pos2] = d;
    lw[pos2] = w;
}

// ---------------------------------------------------------------------------
// Gather (full f32, unchanged from round 4): one wave per task.
// ---------------------------------------------------------------------------
__global__ void gather_kernel(const float* __restrict__ x,
                              const int* __restrict__ off,
                              const int* __restrict__ lsrc,
                              const float* __restrict__ lw,
                              float* __restrict__ mi,
                              float* __restrict__ mo) {
    int wave = (int)((blockIdx.x * (unsigned)blockDim.x + threadIdx.x) >> 6);
    int lane = threadIdx.x & 63;
    if (wave >= TASKS) return;
    int g = lane >> 4;
    int i = lane & 15;
    int e0 = off[wave], e1 = off[wave + 1];

    float acc[8];
#pragma unroll
    for (int r = 0; r < 8; ++r) acc[r] = 0.f;

    for (int base = e0; base < e1; base += 64) {
        int src = 0;
        float w = 0.f;
        int idx = base + lane;
        if (idx < e1) {
            src = lsrc[idx];
            w = lw[idx];
        }
        int cnt = e1 - base;
        if (cnt > 64) cnt = 64;
        int jn = (cnt + 3) >> 2;
        for (int j = 0; j < jn; ++j) {
            int es = j * 4 + g;
            int s = __shfl(src, es);
            float ww = __shfl(w, es);
            const float4* row = (const float4*)(x + (size_t)s * D + i * 8);
            float4 a = row[0];
            float4 b = row[1];
            acc[0] = fmaf(ww, a.x, acc[0]);
            acc[1] = fmaf(ww, a.y, acc[1]);
            acc[2] = fmaf(ww, a.z, acc[2]);
            acc[3] = fmaf(ww, a.w, acc[3]);
            acc[4] = fmaf(ww, b.x, acc[4]);
            acc[5] = fmaf(ww, b.y, acc[5]);
            acc[6] = fmaf(ww, b.z, acc[6]);
            acc[7] = fmaf(ww, b.w, acc[7]);
        }
    }

#pragma unroll
    for (int r = 0; r < 8; ++r) {
        acc[r] += __shfl_xor(acc[r], 32);
        acc[r] += __shfl_xor(acc[r], 16);
    }
    if (g == 0) {
        float* dst = (wave < N_NODES) ? (mi + (size_t)wave * D)
                                      : (mo + (size_t)(wave - N_NODES) * D);
        float4* o = (float4*)(dst + i * 8);
        o[0] = make_float4(acc[0], acc[1], acc[2], acc[3]);
        o[1] = make_float4(acc[4], acc[5], acc[6], acc[7]);
    }
}

// ---------------------------------------------------------------------------
// Weight transpose + hi/lo bf16 split. Wt[n][k] layout so MFMA B-frags are
// 16B-contiguous global loads.
// ---------------------------------------------------------------------------
__global__ void wsplit0(const float* __restrict__ W0, ushort_t* __restrict__ hi,
                        ushort_t* __restrict__ lo) {
    int id = blockIdx.x * 256 + threadIdx.x;     // 128*384
    if (id >= 128 * K0) return;
    int n = id / K0, k = id % K0;
    float a = W0[k * 128 + n];
    ushort_t h = f2bf(a);
    hi[id] = h;
    lo[id] = f2bf(a - bf2f(h));
}

__global__ void wsplitL(const float* __restrict__ W, ushort_t* __restrict__ hi,
                        ushort_t* __restrict__ lo) {
    int id = blockIdx.x * 256 + threadIdx.x;     // 3*128*128
    if (id >= 3 * 128 * KL) return;
    int l = id / (128 * KL), r = id % (128 * KL);
    int n = r / KL, k = r % KL;
    float a = W[l * 128 * KL + k * 128 + n];
    ushort_t h = f2bf(a);
    hi[id] = h;
    lo[id] = f2bf(a - bf2f(h));
}

// ---------------------------------------------------------------------------
// Layer 0 MFMA: h = tanh(LN(concat(mi,mo,x) @ W0 + b0)), K=384.
// Block = 256 thr = 4 waves; M-tile 32 nodes; wave w owns cols [32w,32w+32).
// Split precision: D += Ahi*Bhi + Alo*Bhi + Ahi*Blo  (~f32 accurate).
// mo lives in d_out; output h also d_out (block reads exactly its 32 rows).
// ---------------------------------------------------------------------------
__global__ __launch_bounds__(256, 4) void layer0_mfma(
    const float* __restrict__ mi, const float* mo, const float* __restrict__ x,
    const ushort_t* __restrict__ Bh, const ushort_t* __restrict__ Bl,
    const float* __restrict__ b0, const float* __restrict__ g0,
    const float* __restrict__ be0, float* h) {
    __shared__ __align__(16) char smem[2 * 32 * PAD0 * 2];   // 50176 B (union w/ sout)
    __shared__ float red[32][8][2];
    __shared__ float smv[32][2];
    ushort_t* Ahi = (ushort_t*)smem;
    ushort_t* Alo = Ahi + 32 * PAD0;
    float* sout = (float*)smem;

    int t = threadIdx.x;
    int node0 = blockIdx.x * 32;

    // stage A = concat(mi,mo,x) rows -> hi/lo bf16 in LDS
#pragma unroll
    for (int i = 0; i < 12; ++i) {
        int id = i * 256 + t;                 // 0..3071 (32 rows x 96 float4)
        int r = id / 96;
        int c = (id % 96) * 4;
        const float* src = (c < 128) ? (mi + (size_t)(node0 + r) * D + c)
                         : (c < 256) ? (mo + (size_t)(node0 + r) * D + (c - 128))
                                     : (x + (size_t)(node0 + r) * D + (c - 256));
        float4 v = *(const float4*)src;
        ushort_t h0 = f2bf(v.x), h1 = f2bf(v.y), h2 = f2bf(v.z), h3 = f2bf(v.w);
        ushort_t l0 = f2bf(v.x - bf2f(h0)), l1 = f2bf(v.y - bf2f(h1));
        ushort_t l2 = f2bf(v.z - bf2f(h2)), l3 = f2bf(v.w - bf2f(h3));
        *(ull*)&Ahi[r * PAD0 + c] = (ull)h0 | ((ull)h1 << 16) | ((ull)h2 << 32) | ((ull)h3 << 48);
        *(ull*)&Alo[r * PAD0 + c] = (ull)l0 | ((ull)l1 << 16) | ((ull)l2 << 32) | ((ull)l3 << 48);
    }
    __syncthreads();

    int lane = t & 63, wv = t >> 6;
    int quad = lane >> 4, m15 = lane & 15;
    int cw = wv * 32;

    f32x4 acc[2][2];
#pragma unroll
    for (int rt = 0; rt < 2; ++rt)
#pragma unroll
        for (int ct = 0; ct < 2; ++ct) acc[rt][ct] = (f32x4)0.f;

    for (int k0 = 0; k0 < K0; k0 += 32) {
        int ka = k0 + quad * 8;
        short8 ah0 = *(const short8*)&Ahi[(m15) * PAD0 + ka];
        short8 ah1 = *(const short8*)&Ahi[(16 + m15) * PAD0 + ka];
        short8 al0 = *(const short8*)&Alo[(m15) * PAD0 + ka];
        short8 al1 = *(const short8*)&Alo[(16 + m15) * PAD0 + ka];
        short8 bh0 = *(const short8*)(Bh + (size_t)(cw + m15) * K0 + ka);
        short8 bh1 = *(const short8*)(Bh + (size_t)(cw + 16 + m15) * K0 + ka);
        short8 bl0 = *(const short8*)(Bl + (size_t)(cw + m15) * K0 + ka);
        short8 bl1 = *(const short8*)(Bl + (size_t)(cw + 16 + m15) * K0 + ka);
        acc[0][0] = __builtin_amdgcn_mfma_f32_16x16x32_bf16(ah0, bh0, acc[0][0], 0, 0, 0);
        acc[0][1] = __builtin_amdgcn_mfma_f32_16x16x32_bf16(ah0, bh1, acc[0][1], 0, 0, 0);
        acc[1][0] = __builtin_amdgcn_mfma_f32_16x16x32_bf16(ah1, bh0, acc[1][0], 0, 0, 0);
        acc[1][1] = __builtin_amdgcn_mfma_f32_16x16x32_bf16(ah1, bh1, acc[1][1], 0, 0, 0);
        acc[0][0] = __builtin_amdgcn_mfma_f32_16x16x32_bf16(al0, bh0, acc[0][0], 0, 0, 0);
        acc[0][1] = __builtin_amdgcn_mfma_f32_16x16x32_bf16(al0, bh1, acc[0][1], 0, 0, 0);
        acc[1][0] = __builtin_amdgcn_mfma_f32_16x16x32_bf16(al1, bh0, acc[1][0], 0, 0, 0);
        acc[1][1] = __builtin_amdgcn_mfma_f32_16x16x32_bf16(al1, bh1, acc[1][1], 0, 0, 0);
        acc[0][0] = __builtin_amdgcn_mfma_f32_16x16x32_bf16(ah0, bl0, acc[0][0], 0, 0, 0);
        acc[0][1] = __builtin_amdgcn_mfma_f32_16x16x32_bf16(ah0, bl1, acc[0][1], 0, 0, 0);
        acc[1][0] = __builtin_amdgcn_mfma_f32_16x16x32_bf16(ah1, bl0, acc[1][0], 0, 0, 0);
        acc[1][1] = __builtin_amdgcn_mfma_f32_16x16x32_bf16(ah1, bl1, acc[1][1], 0, 0, 0);
    }
    __syncthreads();   // all A-tile reads done before smem is reused as sout

    float bc0 = b0[cw + m15], bc1 = b0[cw + 16 + m15];
#pragma unroll
    for (int rt = 0; rt < 2; ++rt)
#pragma unroll
        for (int ct = 0; ct < 2; ++ct) {
            float bc = ct ? bc1 : bc0;
            int col = cw + ct * 16 + m15;
#pragma unroll
            for (int reg = 0; reg < 4; ++reg) {
                int row = rt * 16 + quad * 4 + reg;
                sout[row * SSTR + col] = acc[rt][ct][reg] + bc;
            }
        }
    __syncthreads();

    {
        int r = t >> 3, p = t & 7;
        float s = 0.f, s2 = 0.f;
        for (int c = p * 16; c < p * 16 + 16; ++c) {
            float v = sout[r * SSTR + c];
            s += v; s2 += v * v;
        }
        red[r][p][0] = s; red[r][p][1] = s2;
    }
    __syncthreads();
    if (t < 32) {
        float ss = 0.f, ss2 = 0.f;
#pragma unroll
        for (int q = 0; q < 8; ++q) { ss += red[t][q][0]; ss2 += red[t][q][1]; }
        float m = ss * (1.0f / D);
        float var = ss2 * (1.0f / D) - m * m;
        smv[t][0] = m;
        smv[t][1] = rsqrtf(var + EPS);
    }
    __syncthreads();

#pragma unroll
    for (int pass = 0; pass < 4; ++pass) {
        int r = pass * 8 + (t >> 5);
        int c = (t & 31) * 4;
        float mm = smv[r][0], rs = smv[r][1];
        float4 sv = *(const float4*)&sout[r * SSTR + c];
        float4 gv = *(const float4*)&g0[c];
        float4 bv = *(const float4*)&be0[c];
        float4 o;
        o.x = tanh_fast((sv.x - mm) * rs * gv.x + bv.x);
        o.y = tanh_fast((sv.y - mm) * rs * gv.y + bv.y);
        o.z = tanh_fast((sv.z - mm) * rs * gv.z + bv.z);
        o.w = tanh_fast((sv.w - mm) * rs * gv.w + bv.w);
        *(float4*)&h[(size_t)(node0 + r) * D + c] = o;
    }
}

// ---------------------------------------------------------------------------
// Layers 1..3 MFMA: h = tanh(LN(h @ W + b)), K=128, in-place safe.
// ---------------------------------------------------------------------------
__global__ __launch_bounds__(256, 4) void layer_mfma(
    const float* hin,
    const ushort_t* __restrict__ Bh, const ushort_t* __restrict__ Bl,
    const float* __restrict__ b, const float* __restrict__ g,
    const float* __restrict__ be, float* hout) {
    __shared__ __align__(16) char smem[2 * 32 * PADL * 2];   // 17408 B (union w/ sout 16896)
    __shared__ float red[32][8][2];
    __shared__ float smv[32][2];
    ushort_t* Ahi = (ushort_t*)smem;
    ushort_t* Alo = Ahi + 32 * PADL;
    float* sout = (float*)smem;

    int t = threadIdx.x;
    int node0 = blockIdx.x * 32;

#pragma unroll
    for (int i = 0; i < 4; ++i) {
        int id = i * 256 + t;                 // 32 rows x 32 float4
        int r = id >> 5;
        int c = (id & 31) * 4;
        float4 v = *(const float4*)&hin[(size_t)(node0 + r) * D + c];
        ushort_t h0 = f2bf(v.x), h1 = f2bf(v.y), h2 = f2bf(v.z), h3 = f2bf(v.w);
        ushort_t l0 = f2bf(v.x - bf2f(h0)), l1 = f2bf(v.y - bf2f(h1));
        ushort_t l2 = f2bf(v.z - bf2f(h2)), l3 = f2bf(v.w - bf2f(h3));
        *(ull*)&Ahi[r * PADL + c] = (ull)h0 | ((ull)h1 << 16) | ((ull)h2 << 32) | ((ull)h3 << 48);
        *(ull*)&Alo[r * PADL + c] = (ull)l0 | ((ull)l1 << 16) | ((ull)l2 << 32) | ((ull)l3 << 48);
    }
    __syncthreads();

    int lane = t & 63, wv = t >> 6;
    int quad = lane >> 4, m15 = lane & 15;
    int cw = wv * 32;

    f32x4 acc[2][2];
#pragma unroll
    for (int rt = 0; rt < 2; ++rt)
#pragma unroll
        for (int ct = 0; ct < 2; ++ct) acc[rt][ct] = (f32x4)0.f;

#pragma unroll
    for (int k0 = 0; k0 < KL; k0 += 32) {
        int ka = k0 + quad * 8;
        short8 ah0 = *(const short8*)&Ahi[(m15) * PADL + ka];
        short8 ah1 = *(const short8*)&Ahi[(16 + m15) * PADL + ka];
        short8 al0 = *(const short8*)&Alo[(m15) * PADL + ka];
        short8 al1 = *(const short8*)&Alo[(16 + m15) * PADL + ka];
        short8 bh0 = *(const short8*)(Bh + (size_t)(cw + m15) * KL + ka);
        short8 bh1 = *(const short8*)(Bh + (size_t)(cw + 16 + m15) * KL + ka);
        short8 bl0 = *(const short8*)(Bl + (size_t)(cw + m15) * KL + ka);
        short8 bl1 = *(const short8*)(Bl + (size_t)(cw + 16 + m15) * KL + ka);
        acc[0][0] = __builtin_amdgcn_mfma_f32_16x16x32_bf16(ah0, bh0, acc[0][0], 0, 0, 0);
        acc[0][1] = __builtin_amdgcn_mfma_f32_16x16x32_bf16(ah0, bh1, acc[0][1], 0, 0, 0);
        acc[1][0] = __builtin_amdgcn_mfma_f32_16x16x32_bf16(ah1, bh0, acc[1][0], 0, 0, 0);
        acc[1][1] = __builtin_amdgcn_mfma_f32_16x16x32_bf16(ah1, bh1, acc[1][1], 0, 0, 0);
        acc[0][0] = __builtin_amdgcn_mfma_f32_16x16x32_bf16(al0, bh0, acc[0][0], 0, 0, 0);
        acc[0][1] = __builtin_amdgcn_mfma_f32_16x16x32_bf16(al0, bh1, acc[0][1], 0, 0, 0);
        acc[1][0] = __builtin_amdgcn_mfma_f32_16x16x32_bf16(al1, bh0, acc[1][0], 0, 0, 0);
        acc[1][1] = __builtin_amdgcn_mfma_f32_16x16x32_bf16(al1, bh1, acc[1][1], 0, 0, 0);
        acc[0][0] = __builtin_amdgcn_mfma_f32_16x16x32_bf16(ah0, bl0, acc[0][0], 0, 0, 0);
        acc[0][1] = __builtin_amdgcn_mfma_f32_16x16x32_bf16(ah0, bl1, acc[0][1], 0, 0, 0);
        acc[1][0] = __builtin_amdgcn_mfma_f32_16x16x32_bf16(ah1, bl0, acc[1][0], 0, 0, 0);
        acc[1][1] = __builtin_amdgcn_mfma_f32_16x16x32_bf16(ah1, bl1, acc[1][1], 0, 0, 0);
    }
    __syncthreads();

    float bc0 = b[cw + m15], bc1 = b[cw + 16 + m15];
#pragma unroll
    for (int rt = 0; rt < 2; ++rt)
#pragma unroll
        for (int ct = 0; ct < 2; ++ct) {
            float bc = ct ? bc1 : bc0;
            int col = cw + ct * 16 + m15;
#pragma unroll
            for (int reg = 0; reg < 4; ++reg) {
                int row = rt * 16 + quad * 4 + reg;
                sout[row * SSTR + col] = acc[rt][ct][reg] + bc;
            }
        }
    __syncthreads();

    {
        int r = t >> 3, p = t & 7;
        float s = 0.f, s2 = 0.f;
        for (int c = p * 16; c < p * 16 + 16; ++c) {
            float v = sout[r * SSTR + c];
            s += v; s2 += v * v;
        }
        red[r][p][0] = s; red[r][p][1] = s2;
    }
    __syncthreads();
    if (t < 32) {
        float ss = 0.f, ss2 = 0.f;
#pragma unroll
        for (int q = 0; q < 8; ++q) { ss += red[t][q][0]; ss2 += red[t][q][1]; }
        float m = ss * (1.0f / D);
        float var = ss2 * (1.0f / D) - m * m;
        smv[t][0] = m;
        smv[t][1] = rsqrtf(var + EPS);
    }
    __syncthreads();

#pragma unroll
    for (int pass = 0; pass < 4; ++pass) {
        int r = pass * 8 + (t >> 5);
        int c = (t & 31) * 4;
        float mm = smv[r][0], rs = smv[r][1];
        float4 sv = *(const float4*)&sout[r * SSTR + c];
        float4 gv = *(const float4*)&g[c];
        float4 bv = *(const float4*)&be[c];
        float4 o;
        o.x = tanh_fast((sv.x - mm) * rs * gv.x + bv.x);
        o.y = tanh_fast((sv.y - mm) * rs * gv.y + bv.y);
        o.z = tanh_fast((sv.z - mm) * rs * gv.z + bv.z);
        o.w = tanh_fast((sv.w - mm) * rs * gv.w + bv.w);
        *(float4*)&hout[(size_t)(node0 + r) * D + c] = o;
    }
}

static inline char* align64(char* p) {
    return (char*)(((uintptr_t)p + 63) & ~(uintptr_t)63);
}

extern "C" void kernel_launch(void* const* d_in, const int* in_sizes, int n_in,
                              void* d_out, int out_size, void* d_ws, size_t ws_size,
                              hipStream_t stream) {
    const float* x   = (const float*)d_in[0];
    const float* e   = (const float*)d_in[1];
    const int*   ei  = (const int*)d_in[2];
    const float* W0  = (const float*)d_in[3];
    const float* b0  = (const float*)d_in[4];
    const float* g0  = (const float*)d_in[5];
    const float* be0 = (const float*)d_in[6];
    const float* W   = (const float*)d_in[7];
    const float* b   = (const float*)d_in[8];
    const float* g   = (const float*)d_in[9];
    const float* be  = (const float*)d_in[10];
    float* out = (float*)d_out;

    const int* sv = ei;              // edge_index[0] = start
    const int* dv = ei + N_EDGES;    // edge_index[1] = end

    // workspace layout (~79 MB); mo lives in d_out (51.2 MB scratch)
    char* p = (char*)d_ws;
    int* cnt = (int*)p;        p = align64(p + (size_t)NCNT * 4);
    int* off = (int*)p;        p = align64(p + (size_t)OFF_PAD * 4);
    int* aux = (int*)p;        p = align64(p + 256 * 4);
    int* lsrc = (int*)p;       p = align64(p + (size_t)2 * N_EDGES * 4);
    float* lw = (float*)p;     p = align64(p + (size_t)2 * N_EDGES * 4);
    float* mi = (float*)p;     p = align64(p + (size_t)N_NODES * D * 4);
    ushort_t* w0h = (ushort_t*)p;  p = align64(p + (size_t)128 * K0 * 2);
    ushort_t* w0l = (ushort_t*)p;  p = align64(p + (size_t)128 * K0 * 2);
    ushort_t* wlh = (ushort_t*)p;  p = align64(p + (size_t)3 * 128 * KL * 2);
    ushort_t* wll = (ushort_t*)p;
    float* mo = out;                 // d_out as scratch

    hipMemsetAsync(cnt, 0, NCNT * sizeof(int), stream);

    wsplit0<<<(128 * K0 + 255) / 256, 256, 0, stream>>>(W0, w0h, w0l);
    wsplitL<<<(3 * 128 * KL + 255) / 256, 256, 0, stream>>>(W, wlh, wll);

    hist_kernel<<<(N_EDGES + 255) / 256, 256, 0, stream>>>(sv, dv, cnt);
    scan_a<<<SCAN_BLOCKS, 256, 0, stream>>>(cnt, off, aux);
    scan_b<<<1, 256, 0, stream>>>(aux);
    scan_c<<<SCAN_BLOCKS, 256, 0, stream>>>(off, aux);
    fill_kernel<<<(N_EDGES + 255) / 256, 256, 0, stream>>>(sv, dv, e, off, cnt, lsrc, lw);

    gather_kernel<<<TASKS / 4, 256, 0, stream>>>(x, off, lsrc, lw, mi, mo);

    layer0_mfma<<<N_NODES / 32, 256, 0, stream>>>(mi, mo, x, w0h, w0l,
                                                  b0, g0, be0, out);

    for (int i = 0; i < 3; ++i) {
        layer_mfma<<<N_NODES / 32, 256, 0, stream>>>(
            out, wlh + (size_t)i * 128 * KL, wll + (size_t)i * 128 * KL,
            b + (size_t)i * D, g + (size_t)i * D, be + (size_t)i * D, out);
    }
}

// Round 7
// 777.874 us; speedup vs baseline: 2.5409x; 1.0761x over previous
//
#include <hip/hip_runtime.h>
#include <math.h>

#define N_NODES 100000
#define N_EDGES 1600000
#define D 128
#define EPS 1e-5f
#define NCNT (2 * N_NODES)
#define SCAN_CHUNK 1024
#define SCAN_BLOCKS ((NCNT + SCAN_CHUNK - 1) / SCAN_CHUNK)   // 196
#define OFF_PAD (SCAN_BLOCKS * SCAN_CHUNK + 1)
#define TASKS (2 * N_NODES)

#define K0 384
#define KL 128
#define PAD0 (K0 + 8)     // bf16 elems per LDS row, layer0
#define PADL (KL + 8)     // bf16 elems per LDS row, layers 1-3
#define SSTR 132          // f32 sout row stride

typedef unsigned short ushort_t;
typedef unsigned long long ull;
typedef short short8 __attribute__((ext_vector_type(8)));     // MFMA A/B frag
typedef _Float16 half8 __attribute__((ext_vector_type(8)));   // fp16 x row chunk
typedef _Float16 half4v __attribute__((ext_vector_type(4)));
typedef float f32x4 __attribute__((ext_vector_type(4)));      // MFMA C/D frag

static __device__ __forceinline__ float bf2f(ushort_t u) {
    return __uint_as_float(((unsigned)u) << 16);
}
static __device__ __forceinline__ ushort_t f2bf(float f) {
    unsigned u = __float_as_uint(f);
    u += 0x7FFF + ((u >> 16) & 1);          // RNE
    return (ushort_t)(u >> 16);
}
static __device__ __forceinline__ float tanh_fast(float v) {
    return 1.0f - 2.0f / (__expf(2.0f * v) + 1.0f);
}

// ---------------------------------------------------------------------------
// x (f32) -> xh (fp16), 4 elems/thread. fp16: rel err 2^-11 (vs bf16 2^-8).
// ---------------------------------------------------------------------------
__global__ void cvt_x_kernel(const float* __restrict__ x, _Float16* __restrict__ xh) {
    int i = blockIdx.x * blockDim.x + threadIdx.x;   // 3.2M threads
    float4 v = ((const float4*)x)[i];
    half4v h;
    h[0] = (_Float16)v.x; h[1] = (_Float16)v.y;
    h[2] = (_Float16)v.z; h[3] = (_Float16)v.w;
    ((half4v*)xh)[i] = h;
}

// ---------------------------------------------------------------------------
// CSR build
// ---------------------------------------------------------------------------
__global__ void hist_kernel(const int* __restrict__ sv, const int* __restrict__ dv,
                            int* __restrict__ cnt) {
    int e = blockIdx.x * blockDim.x + threadIdx.x;
    if (e >= N_EDGES) return;
    atomicAdd(&cnt[dv[e]], 1);
    atomicAdd(&cnt[N_NODES + sv[e]], 1);
}

__global__ void scan_a(const int* __restrict__ cnt, int* __restrict__ off,
                       int* __restrict__ aux) {
    __shared__ int lds[256];
    int tid = threadIdx.x;
    int base = blockIdx.x * SCAN_CHUNK + tid * 4;
    int v0 = (base + 0 < NCNT) ? cnt[base + 0] : 0;
    int v1 = (base + 1 < NCNT) ? cnt[base + 1] : 0;
    int v2 = (base + 2 < NCNT) ? cnt[base + 2] : 0;
    int v3 = (base + 3 < NCNT) ? cnt[base + 3] : 0;
    int tot = v0 + v1 + v2 + v3;
    lds[tid] = tot;
    __syncthreads();
    for (int s = 1; s < 256; s <<= 1) {
        int add = (tid >= s) ? lds[tid - s] : 0;
        __syncthreads();
        lds[tid] += add;
        __syncthreads();
    }
    int excl = lds[tid] - tot;
    off[base + 1] = excl + v0;
    off[base + 2] = excl + v0 + v1;
    off[base + 3] = excl + v0 + v1 + v2;
    off[base + 4] = excl + tot;
    if (tid == 255) aux[blockIdx.x] = lds[255];
}

__global__ void scan_b(int* __restrict__ aux) {
    __shared__ int lds[256];
    int tid = threadIdx.x;
    int v = (tid < SCAN_BLOCKS) ? aux[tid] : 0;
    lds[tid] = v;
    __syncthreads();
    for (int s = 1; s < 256; s <<= 1) {
        int add = (tid >= s) ? lds[tid - s] : 0;
        __syncthreads();
        lds[tid] += add;
        __syncthreads();
    }
    aux[tid] = lds[tid] - v;
}

__global__ void scan_c(int* __restrict__ off, const int* __restrict__ aux) {
    int tid = threadIdx.x;
    int add = aux[blockIdx.x];
    int base = blockIdx.x * SCAN_CHUNK + tid * 4;
    off[base + 1] += add;
    off[base + 2] += add;
    off[base + 3] += add;
    off[base + 4] += add;
    if (blockIdx.x == 0 && tid == 0) off[0] = 0;
}

// Fill packed lists: entry = (w15 << 17) | src, where w15 = round(w*32768)
// clamped to 32767 (w in [0,1), src < 2^17). Abs err of w <= 1.5e-5.
__global__ void fill_kernel(const int* __restrict__ sv, const int* __restrict__ dv,
                            const float* __restrict__ ew, const int* __restrict__ off,
                            int* __restrict__ cnt, unsigned* __restrict__ plist) {
    int e = blockIdx.x * blockDim.x + threadIdx.x;
    if (e >= N_EDGES) return;
    int s = sv[e], d = dv[e];
    unsigned wq = (unsigned)(ew[e] * 32768.0f + 0.5f);
    if (wq > 32767u) wq = 32767u;
    int c = atomicSub(&cnt[d], 1);
    plist[off[d] + c - 1] = (wq << 17) | (unsigned)s;
    int c2 = atomicSub(&cnt[N_NODES + s], 1);
    plist[off[N_NODES + s] + c2 - 1] = (wq << 17) | (unsigned)d;
}

// ---------------------------------------------------------------------------
// Gather: one wave per task (task < N: mi row, else mo row in d_out).
// fp16 x rows (256 B), one 16 B load per lane per edge; 4 lane-groups of 16
// process 4 edges concurrently, loop unrolled x4 -> 4 loads in flight.
// f32 accumulate + f32 output.
// ---------------------------------------------------------------------------
__global__ void gather_kernel(const _Float16* __restrict__ xh,
                              const int* __restrict__ off,
                              const unsigned* __restrict__ plist,
                              float* __restrict__ mi,
                              float* __restrict__ mo) {
    int wave = (int)((blockIdx.x * (unsigned)blockDim.x + threadIdx.x) >> 6);
    int lane = threadIdx.x & 63;
    if (wave >= TASKS) return;
    int g = lane >> 4;        // edge slot within quad
    int i = lane & 15;        // 16 B chunk within fp16 row
    int e0 = off[wave], e1 = off[wave + 1];
    const float wsc = 1.0f / 32768.0f;

    float acc[8];
#pragma unroll
    for (int r = 0; r < 8; ++r) acc[r] = 0.f;

    for (int base = e0; base < e1; base += 64) {
        unsigned pv = 0;      // pv=0 => w=0 contribution (safe pad)
        int idx = base + lane;
        if (idx < e1) pv = plist[idx];
        int cnt = e1 - base;
        if (cnt > 64) cnt = 64;
        int jn = (cnt + 3) >> 2;
        int j = 0;
        for (; j + 3 < jn; j += 4) {
            unsigned p0 = (unsigned)__shfl((int)pv, (j + 0) * 4 + g);
            unsigned p1 = (unsigned)__shfl((int)pv, (j + 1) * 4 + g);
            unsigned p2 = (unsigned)__shfl((int)pv, (j + 2) * 4 + g);
            unsigned p3 = (unsigned)__shfl((int)pv, (j + 3) * 4 + g);
            half8 v0 = *(const half8*)(xh + (size_t)(p0 & 0x1FFFF) * D + i * 8);
            half8 v1 = *(const half8*)(xh + (size_t)(p1 & 0x1FFFF) * D + i * 8);
            half8 v2 = *(const half8*)(xh + (size_t)(p2 & 0x1FFFF) * D + i * 8);
            half8 v3 = *(const half8*)(xh + (size_t)(p3 & 0x1FFFF) * D + i * 8);
            float w0 = (float)(p0 >> 17) * wsc;
            float w1 = (float)(p1 >> 17) * wsc;
            float w2 = (float)(p2 >> 17) * wsc;
            float w3 = (float)(p3 >> 17) * wsc;
#pragma unroll
            for (int r = 0; r < 8; ++r) acc[r] = fmaf(w0, (float)v0[r], acc[r]);
#pragma unroll
            for (int r = 0; r < 8; ++r) acc[r] = fmaf(w1, (float)v1[r], acc[r]);
#pragma unroll
            for (int r = 0; r < 8; ++r) acc[r] = fmaf(w2, (float)v2[r], acc[r]);
#pragma unroll
            for (int r = 0; r < 8; ++r) acc[r] = fmaf(w3, (float)v3[r], acc[r]);
        }
        for (; j < jn; ++j) {
            unsigned p0 = (unsigned)__shfl((int)pv, j * 4 + g);
            half8 v0 = *(const half8*)(xh + (size_t)(p0 & 0x1FFFF) * D + i * 8);
            float w0 = (float)(p0 >> 17) * wsc;
#pragma unroll
            for (int r = 0; r < 8; ++r) acc[r] = fmaf(w0, (float)v0[r], acc[r]);
        }
    }

#pragma unroll
    for (int r = 0; r < 8; ++r) {
        acc[r] += __shfl_xor(acc[r], 32);
        acc[r] += __shfl_xor(acc[r], 16);
    }
    if (g == 0) {
        float* dst = (wave < N_NODES) ? (mi + (size_t)wave * D)
                                      : (mo + (size_t)(wave - N_NODES) * D);
        float4* o = (float4*)(dst + i * 8);
        o[0] = make_float4(acc[0], acc[1], acc[2], acc[3]);
        o[1] = make_float4(acc[4], acc[5], acc[6], acc[7]);
    }
}

// ---------------------------------------------------------------------------
// Weight transpose + hi/lo bf16 split (Wt[n][k] layout).
// ---------------------------------------------------------------------------
__global__ void wsplit0(const float* __restrict__ W0, ushort_t* __restrict__ hi,
                        ushort_t* __restrict__ lo) {
    int id = blockIdx.x * 256 + threadIdx.x;     // 128*384
    if (id >= 128 * K0) return;
    int n = id / K0, k = id % K0;
    float a = W0[k * 128 + n];
    ushort_t h = f2bf(a);
    hi[id] = h;
    lo[id] = f2bf(a - bf2f(h));
}

__global__ void wsplitL(const float* __restrict__ W, ushort_t* __restrict__ hi,
                        ushort_t* __restrict__ lo) {
    int id = blockIdx.x * 256 + threadIdx.x;     // 3*128*128
    if (id >= 3 * 128 * KL) return;
    int l = id / (128 * KL), r = id % (128 * KL);
    int n = r / KL, k = r % KL;
    float a = W[l * 128 * KL + k * 128 + n];
    ushort_t h = f2bf(a);
    hi[id] = h;
    lo[id] = f2bf(a - bf2f(h));
}

// ---------------------------------------------------------------------------
// Layer 0 MFMA: h = tanh(LN(concat(mi,mo,x) @ W0 + b0)), K=384.
// Split precision: D += Ahi*Bhi + Alo*Bhi + Ahi*Blo.
// ---------------------------------------------------------------------------
__global__ __launch_bounds__(256, 4) void layer0_mfma(
    const float* __restrict__ mi, const float* mo, const float* __restrict__ x,
    const ushort_t* __restrict__ Bh, const ushort_t* __restrict__ Bl,
    const float* __restrict__ b0, const float* __restrict__ g0,
    const float* __restrict__ be0, float* h) {
    __shared__ __align__(16) char smem[2 * 32 * PAD0 * 2];
    __shared__ float red[32][8][2];
    __shared__ float smv[32][2];
    ushort_t* Ahi = (ushort_t*)smem;
    ushort_t* Alo = Ahi + 32 * PAD0;
    float* sout = (float*)smem;

    int t = threadIdx.x;
    int node0 = blockIdx.x * 32;

#pragma unroll
    for (int i = 0; i < 12; ++i) {
        int id = i * 256 + t;
        int r = id / 96;
        int c = (id % 96) * 4;
        const float* src = (c < 128) ? (mi + (size_t)(node0 + r) * D + c)
                         : (c < 256) ? (mo + (size_t)(node0 + r) * D + (c - 128))
                                     : (x + (size_t)(node0 + r) * D + (c - 256));
        float4 v = *(const float4*)src;
        ushort_t h0 = f2bf(v.x), h1 = f2bf(v.y), h2 = f2bf(v.z), h3 = f2bf(v.w);
        ushort_t l0 = f2bf(v.x - bf2f(h0)), l1 = f2bf(v.y - bf2f(h1));
        ushort_t l2 = f2bf(v.z - bf2f(h2)), l3 = f2bf(v.w - bf2f(h3));
        *(ull*)&Ahi[r * PAD0 + c] = (ull)h0 | ((ull)h1 << 16) | ((ull)h2 << 32) | ((ull)h3 << 48);
        *(ull*)&Alo[r * PAD0 + c] = (ull)l0 | ((ull)l1 << 16) | ((ull)l2 << 32) | ((ull)l3 << 48);
    }
    __syncthreads();

    int lane = t & 63, wv = t >> 6;
    int quad = lane >> 4, m15 = lane & 15;
    int cw = wv * 32;

    f32x4 acc[2][2];
#pragma unroll
    for (int rt = 0; rt < 2; ++rt)
#pragma unroll
        for (int ct = 0; ct < 2; ++ct) acc[rt][ct] = (f32x4)0.f;

    for (int k0 = 0; k0 < K0; k0 += 32) {
        int ka = k0 + quad * 8;
        short8 ah0 = *(const short8*)&Ahi[(m15) * PAD0 + ka];
        short8 ah1 = *(const short8*)&Ahi[(16 + m15) * PAD0 + ka];
        short8 al0 = *(const short8*)&Alo[(m15) * PAD0 + ka];
        short8 al1 = *(const short8*)&Alo[(16 + m15) * PAD0 + ka];
        short8 bh0 = *(const short8*)(Bh + (size_t)(cw + m15) * K0 + ka);
        short8 bh1 = *(const short8*)(Bh + (size_t)(cw + 16 + m15) * K0 + ka);
        short8 bl0 = *(const short8*)(Bl + (size_t)(cw + m15) * K0 + ka);
        short8 bl1 = *(const short8*)(Bl + (size_t)(cw + 16 + m15) * K0 + ka);
        acc[0][0] = __builtin_amdgcn_mfma_f32_16x16x32_bf16(ah0, bh0, acc[0][0], 0, 0, 0);
        acc[0][1] = __builtin_amdgcn_mfma_f32_16x16x32_bf16(ah0, bh1, acc[0][1], 0, 0, 0);
        acc[1][0] = __builtin_amdgcn_mfma_f32_16x16x32_bf16(ah1, bh0, acc[1][0], 0, 0, 0);
        acc[1][1] = __builtin_amdgcn_mfma_f32_16x16x32_bf16(ah1, bh1, acc[1][1], 0, 0, 0);
        acc[0][0] = __builtin_amdgcn_mfma_f32_16x16x32_bf16(al0, bh0, acc[0][0], 0, 0, 0);
        acc[0][1] = __builtin_amdgcn_mfma_f32_16x16x32_bf16(al0, bh1, acc[0][1], 0, 0, 0);
        acc[1][0] = __builtin_amdgcn_mfma_f32_16x16x32_bf16(al1, bh0, acc[1][0], 0, 0, 0);
        acc[1][1] = __builtin_amdgcn_mfma_f32_16x16x32_bf16(al1, bh1, acc[1][1], 0, 0, 0);
        acc[0][0] = __builtin_amdgcn_mfma_f32_16x16x32_bf16(ah0, bl0, acc[0][0], 0, 0, 0);
        acc[0][1] = __builtin_amdgcn_mfma_f32_16x16x32_bf16(ah0, bl1, acc[0][1], 0, 0, 0);
        acc[1][0] = __builtin_amdgcn_mfma_f32_16x16x32_bf16(ah1, bl0, acc[1][0], 0, 0, 0);
        acc[1][1] = __builtin_amdgcn_mfma_f32_16x16x32_bf16(ah1, bl1, acc[1][1], 0, 0, 0);
    }
    __syncthreads();

    float bc0 = b0[cw + m15], bc1 = b0[cw + 16 + m15];
#pragma unroll
    for (int rt = 0; rt < 2; ++rt)
#pragma unroll
        for (int ct = 0; ct < 2; ++ct) {
            float bc = ct ? bc1 : bc0;
            int col = cw + ct * 16 + m15;
#pragma unroll
            for (int reg = 0; reg < 4; ++reg) {
                int row = rt * 16 + quad * 4 + reg;
                sout[row * SSTR + col] = acc[rt][ct][reg] + bc;
            }
        }
    __syncthreads();

    {
        int r = t >> 3, p = t & 7;
        float s = 0.f, s2 = 0.f;
        for (int c = p * 16; c < p * 16 + 16; ++c) {
            float v = sout[r * SSTR + c];
            s += v; s2 += v * v;
        }
        red[r][p][0] = s; red[r][p][1] = s2;
    }
    __syncthreads();
    if (t < 32) {
        float ss = 0.f, ss2 = 0.f;
#pragma unroll
        for (int q = 0; q < 8; ++q) { ss += red[t][q][0]; ss2 += red[t][q][1]; }
        float m = ss * (1.0f / D);
        float var = ss2 * (1.0f / D) - m * m;
        smv[t][0] = m;
        smv[t][1] = rsqrtf(var + EPS);
    }
    __syncthreads();

#pragma unroll
    for (int pass = 0; pass < 4; ++pass) {
        int r = pass * 8 + (t >> 5);
        int c = (t & 31) * 4;
        float mm = smv[r][0], rs = smv[r][1];
        float4 sv = *(const float4*)&sout[r * SSTR + c];
        float4 gv = *(const float4*)&g0[c];
        float4 bv = *(const float4*)&be0[c];
        float4 o;
        o.x = tanh_fast((sv.x - mm) * rs * gv.x + bv.x);
        o.y = tanh_fast((sv.y - mm) * rs * gv.y + bv.y);
        o.z = tanh_fast((sv.z - mm) * rs * gv.z + bv.z);
        o.w = tanh_fast((sv.w - mm) * rs * gv.w + bv.w);
        *(float4*)&h[(size_t)(node0 + r) * D + c] = o;
    }
}

// ---------------------------------------------------------------------------
// Layers 1..3 MFMA: h = tanh(LN(h @ W + b)), K=128, in-place safe.
// ---------------------------------------------------------------------------
__global__ __launch_bounds__(256, 4) void layer_mfma(
    const float* hin,
    const ushort_t* __restrict__ Bh, const ushort_t* __restrict__ Bl,
    const float* __restrict__ b, const float* __restrict__ g,
    const float* __restrict__ be, float* hout) {
    __shared__ __align__(16) char smem[2 * 32 * PADL * 2];
    __shared__ float red[32][8][2];
    __shared__ float smv[32][2];
    ushort_t* Ahi = (ushort_t*)smem;
    ushort_t* Alo = Ahi + 32 * PADL;
    float* sout = (float*)smem;

    int t = threadIdx.x;
    int node0 = blockIdx.x * 32;

#pragma unroll
    for (int i = 0; i < 4; ++i) {
        int id = i * 256 + t;
        int r = id >> 5;
        int c = (id & 31) * 4;
        float4 v = *(const float4*)&hin[(size_t)(node0 + r) * D + c];
        ushort_t h0 = f2bf(v.x), h1 = f2bf(v.y), h2 = f2bf(v.z), h3 = f2bf(v.w);
        ushort_t l0 = f2bf(v.x - bf2f(h0)), l1 = f2bf(v.y - bf2f(h1));
        ushort_t l2 = f2bf(v.z - bf2f(h2)), l3 = f2bf(v.w - bf2f(h3));
        *(ull*)&Ahi[r * PADL + c] = (ull)h0 | ((ull)h1 << 16) | ((ull)h2 << 32) | ((ull)h3 << 48);
        *(ull*)&Alo[r * PADL + c] = (ull)l0 | ((ull)l1 << 16) | ((ull)l2 << 32) | ((ull)l3 << 48);
    }
    __syncthreads();

    int lane = t & 63, wv = t >> 6;
    int quad = lane >> 4, m15 = lane & 15;
    int cw = wv * 32;

    f32x4 acc[2][2];
#pragma unroll
    for (int rt = 0; rt < 2; ++rt)
#pragma unroll
        for (int ct = 0; ct < 2; ++ct) acc[rt][ct] = (f32x4)0.f;

#pragma unroll
    for (int k0 = 0; k0 < KL; k0 += 32) {
        int ka = k0 + quad * 8;
        short8 ah0 = *(const short8*)&Ahi[(m15) * PADL + ka];
        short8 ah1 = *(const short8*)&Ahi[(16 + m15) * PADL + ka];
        short8 al0 = *(const short8*)&Alo[(m15) * PADL + ka];
        short8 al1 = *(const short8*)&Alo[(16 + m15) * PADL + ka];
        short8 bh0 = *(const short8*)(Bh + (size_t)(cw + m15) * KL + ka);
        short8 bh1 = *(const short8*)(Bh + (size_t)(cw + 16 + m15) * KL + ka);
        short8 bl0 = *(const short8*)(Bl + (size_t)(cw + m15) * KL + ka);
        short8 bl1 = *(const short8*)(Bl + (size_t)(cw + 16 + m15) * KL + ka);
        acc[0][0] = __builtin_amdgcn_mfma_f32_16x16x32_bf16(ah0, bh0, acc[0][0], 0, 0, 0);
        acc[0][1] = __builtin_amdgcn_mfma_f32_16x16x32_bf16(ah0, bh1, acc[0][1], 0, 0, 0);
        acc[1][0] = __builtin_amdgcn_mfma_f32_16x16x32_bf16(ah1, bh0, acc[1][0], 0, 0, 0);
        acc[1][1] = __builtin_amdgcn_mfma_f32_16x16x32_bf16(ah1, bh1, acc[1][1], 0, 0, 0);
        acc[0][0] = __builtin_amdgcn_mfma_f32_16x16x32_bf16(al0, bh0, acc[0][0], 0, 0, 0);
        acc[0][1] = __builtin_amdgcn_mfma_f32_16x16x32_bf16(al0, bh1, acc[0][1], 0, 0, 0);
        acc[1][0] = __builtin_amdgcn_mfma_f32_16x16x32_bf16(al1, bh0, acc[1][0], 0, 0, 0);
        acc[1][1] = __builtin_amdgcn_mfma_f32_16x16x32_bf16(al1, bh1, acc[1][1], 0, 0, 0);
        acc[0][0] = __builtin_amdgcn_mfma_f32_16x16x32_bf16(ah0, bl0, acc[0][0], 0, 0, 0);
        acc[0][1] = __builtin_amdgcn_mfma_f32_16x16x32_bf16(ah0, bl1, acc[0][1], 0, 0, 0);
        acc[1][0] = __builtin_amdgcn_mfma_f32_16x16x32_bf16(ah1, bl0, acc[1][0], 0, 0, 0);
        acc[1][1] = __builtin_amdgcn_mfma_f32_16x16x32_bf16(ah1, bl1, acc[1][1], 0, 0, 0);
    }
    __syncthreads();

    float bc0 = b[cw + m15], bc1 = b[cw + 16 + m15];
#pragma unroll
    for (int rt = 0; rt < 2; ++rt)
#pragma unroll
        for (int ct = 0; ct < 2; ++ct) {
            float bc = ct ? bc1 : bc0;
            int col = cw + ct * 16 + m15;
#pragma unroll
            for (int reg = 0; reg < 4; ++reg) {
                int row = rt * 16 + quad * 4 + reg;
                sout[row * SSTR + col] = acc[rt][ct][reg] + bc;
            }
        }
    __syncthreads();

    {
        int r = t >> 3, p = t & 7;
        float s = 0.f, s2 = 0.f;
        for (int c = p * 16; c < p * 16 + 16; ++c) {
            float v = sout[r * SSTR + c];
            s += v; s2 += v * v;
        }
        red[r][p][0] = s; red[r][p][1] = s2;
    }
    __syncthreads();
    if (t < 32) {
        float ss = 0.f, ss2 = 0.f;
#pragma unroll
        for (int q = 0; q < 8; ++q) { ss += red[t][q][0]; ss2 += red[t][q][1]; }
        float m = ss * (1.0f / D);
        float var = ss2 * (1.0f / D) - m * m;
        smv[t][0] = m;
        smv[t][1] = rsqrtf(var + EPS);
    }
    __syncthreads();

#pragma unroll
    for (int pass = 0; pass < 4; ++pass) {
        int r = pass * 8 + (t >> 5);
        int c = (t & 31) * 4;
        float mm = smv[r][0], rs = smv[r][1];
        float4 sv = *(const float4*)&sout[r * SSTR + c];
        float4 gv = *(const float4*)&g[c];
        float4 bv = *(const float4*)&be[c];
        float4 o;
        o.x = tanh_fast((sv.x - mm) * rs * gv.x + bv.x);
        o.y = tanh_fast((sv.y - mm) * rs * gv.y + bv.y);
        o.z = tanh_fast((sv.z - mm) * rs * gv.z + bv.z);
        o.w = tanh_fast((sv.w - mm) * rs * gv.w + bv.w);
        *(float4*)&hout[(size_t)(node0 + r) * D + c] = o;
    }
}

static inline char* align64(char* p) {
    return (char*)(((uintptr_t)p + 63) & ~(uintptr_t)63);
}

extern "C" void kernel_launch(void* const* d_in, const int* in_sizes, int n_in,
                              void* d_out, int out_size, void* d_ws, size_t ws_size,
                              hipStream_t stream) {
    const float* x   = (const float*)d_in[0];
    const float* e   = (const float*)d_in[1];
    const int*   ei  = (const int*)d_in[2];
    const float* W0  = (const float*)d_in[3];
    const float* b0  = (const float*)d_in[4];
    const float* g0  = (const float*)d_in[5];
    const float* be0 = (const float*)d_in[6];
    const float* W   = (const float*)d_in[7];
    const float* b   = (const float*)d_in[8];
    const float* g   = (const float*)d_in[9];
    const float* be  = (const float*)d_in[10];
    float* out = (float*)d_out;

    const int* sv = ei;              // edge_index[0] = start
    const int* dv = ei + N_EDGES;    // edge_index[1] = end

    // workspace (~91 MB peak). W-split buffers alias the cnt region: cnt is
    // dead after fill_kernel, and wsplit kernels launch after fill.
    char* p = (char*)d_ws;
    char* cnt_base = p;
    int* cnt = (int*)p;           p = align64(p + (size_t)NCNT * 4);          // 0.8 MB
    int* off = (int*)p;           p = align64(p + (size_t)OFF_PAD * 4);       // 0.8 MB
    int* aux = (int*)p;           p = align64(p + 256 * 4);
    unsigned* plist = (unsigned*)p; p = align64(p + (size_t)2 * N_EDGES * 4); // 12.8 MB
    float* mi = (float*)p;        p = align64(p + (size_t)N_NODES * D * 4);   // 51.2 MB
    _Float16* xh = (_Float16*)p;                                              // 25.6 MB
    // aliased into cnt region (total 384 KB < 800 KB):
    char* q = cnt_base;
    ushort_t* w0h = (ushort_t*)q;  q = align64(q + (size_t)128 * K0 * 2);
    ushort_t* w0l = (ushort_t*)q;  q = align64(q + (size_t)128 * K0 * 2);
    ushort_t* wlh = (ushort_t*)q;  q = align64(q + (size_t)3 * 128 * KL * 2);
    ushort_t* wll = (ushort_t*)q;
    float* mo = out;                 // d_out as scratch

    hipMemsetAsync(cnt, 0, NCNT * sizeof(int), stream);

    cvt_x_kernel<<<(N_NODES * D / 4) / 256, 256, 0, stream>>>(x, xh);
    hist_kernel<<<(N_EDGES + 255) / 256, 256, 0, stream>>>(sv, dv, cnt);
    scan_a<<<SCAN_BLOCKS, 256, 0, stream>>>(cnt, off, aux);
    scan_b<<<1, 256, 0, stream>>>(aux);
    scan_c<<<SCAN_BLOCKS, 256, 0, stream>>>(off, aux);
    fill_kernel<<<(N_EDGES + 255) / 256, 256, 0, stream>>>(sv, dv, e, off, cnt, plist);

    // cnt is dead now; its region becomes the W-split buffers.
    wsplit0<<<(128 * K0 + 255) / 256, 256, 0, stream>>>(W0, w0h, w0l);
    wsplitL<<<(3 * 128 * KL + 255) / 256, 256, 0, stream>>>(W, wlh, wll);

    gather_kernel<<<TASKS / 4, 256, 0, stream>>>(xh, off, plist, mi, mo);

    layer0_mfma<<<N_NODES / 32, 256, 0, stream>>>(mi, mo, x, w0h, w0l,
                                                  b0, g0, be0, out);

    for (int i = 0; i < 3; ++i) {
        layer_mfma<<<N_NODES / 32, 256, 0, stream>>>(
            out, wlh + (size_t)i * 128 * KL, wll + (size_t)i * 128 * KL,
            b + (size_t)i * D, g + (size_t)i * D, be + (size_t)i * D, out);
    }
}